// Round 6
// baseline (774.819 us; speedup 1.0000x reference)
//
#include <hip/hip_runtime.h>
#include <math.h>

#define TOK   8192
#define DDIM  1024
#define HDIM  4096
#define NEXP  8
#define CAP   18432   /* 16384 + 8*256 = 72*256 */
#define NMT   72
#define BM    256
#define BN    256

typedef __attribute__((ext_vector_type(8))) short  bfrag;
typedef __attribute__((ext_vector_type(4))) float  ffrag;
typedef __attribute__((ext_vector_type(8))) unsigned short us8;

__device__ __forceinline__ unsigned short f2bf(float f) {
  unsigned int u = __float_as_uint(f);
  u = (u + 0x7FFFu + ((u >> 16) & 1u)) >> 16;   // RNE
  return (unsigned short)u;
}
__device__ __forceinline__ float bf2f(unsigned short u) {
  return __uint_as_float((unsigned int)u << 16);
}

__device__ __forceinline__ void gll16(const void* g, void* l) {
  __builtin_amdgcn_global_load_lds(
      (const __attribute__((address_space(1))) unsigned int*)g,
      (__attribute__((address_space(3))) unsigned int*)l,
      16, 0, 0);
}

// ---- fused transpose+cvt: W1 [8][1024][4096] and W2 [8][4096][1024] -> [C][R] bf16
// 64x64 tile per block; fp32 LDS with XOR swizzle (word = r*64 + (c^r)):
// write side 2-way conflicts (free), read side exactly 2-way (free); us8 stores.
__global__ __launch_bounds__(256) void transpose_cvt2(const float* __restrict__ W1,
                                                      unsigned short* __restrict__ w1t,
                                                      const float* __restrict__ W2,
                                                      unsigned short* __restrict__ w2t) {
  int bid = blockIdx.x;
  const float* in; unsigned short* out; int R, C, tile;
  if (bid < 8192) { in = W1; out = w1t; R = DDIM; C = HDIM; tile = bid; }
  else            { in = W2; out = w2t; R = HDIM; C = DDIM; tile = bid - 8192; }
  int e = tile >> 10;              // 1024 tiles per expert for both shapes
  int t = tile & 1023;
  int tpr = C >> 6;
  int ty = t / tpr, tx = t % tpr;
  size_t bo = (size_t)e * R * C;
  in += bo; out += bo;
  int r0 = ty * 64, c0 = tx * 64;

  __shared__ float t4[4096];
  int tid = threadIdx.x;
  int tr = tid >> 4;
  int tc4 = (tid & 15) * 4;
#pragma unroll
  for (int it = 0; it < 4; ++it) {
    int r = tr + it * 16;
    float4 v = *(const float4*)&in[(size_t)(r0 + r) * C + c0 + tc4];
    t4[r * 64 + ((tc4 + 0) ^ r)] = v.x;
    t4[r * 64 + ((tc4 + 1) ^ r)] = v.y;
    t4[r * 64 + ((tc4 + 2) ^ r)] = v.z;
    t4[r * 64 + ((tc4 + 3) ^ r)] = v.w;
  }
  __syncthreads();
  int og0 = (tid & 7) * 8;
  int oc0 = tid >> 3;              // 0..31
#pragma unroll
  for (int it = 0; it < 2; ++it) {
    int oc = oc0 + it * 32;
    us8 v;
#pragma unroll
    for (int j = 0; j < 8; ++j) {
      int r = og0 + j;
      v[j] = (short)f2bf(t4[r * 64 + (oc ^ r)]);
    }
    *(us8*)&out[(size_t)(c0 + oc) * R + r0 + og0] = v;
  }
}

// ------- gate: logits, top-2, softmax, histogram; fused x fp32->bf16 -------
__global__ __launch_bounds__(64) void gate_kernel(const float* __restrict__ x,
                                                  const float* __restrict__ Wg,
                                                  const float* __restrict__ bg,
                                                  unsigned short* __restrict__ xb,
                                                  int* __restrict__ topi,
                                                  float* __restrict__ topw,
                                                  int* __restrict__ cnt) {
  int t = blockIdx.x, l = threadIdx.x;
  const float4* xr = (const float4*)(x + (size_t)t * DDIM);
  ushort4* xo = (ushort4*)(xb + (size_t)t * DDIM);
  const float4* wg = (const float4*)Wg;
  float acc[8];
#pragma unroll
  for (int e = 0; e < 8; ++e) acc[e] = 0.f;
#pragma unroll
  for (int g = 0; g < 4; ++g) {
    int idx = g * 64 + l;
    float4 xv = xr[idx];
    xo[idx] = (ushort4){ f2bf(xv.x), f2bf(xv.y), f2bf(xv.z), f2bf(xv.w) };
    int dbase = idx * 4;
    float xs[4] = { xv.x, xv.y, xv.z, xv.w };
#pragma unroll
    for (int c = 0; c < 4; ++c) {
      float4 w0 = wg[(dbase + c) * 2 + 0];
      float4 w1 = wg[(dbase + c) * 2 + 1];
      acc[0] += xs[c] * w0.x; acc[1] += xs[c] * w0.y;
      acc[2] += xs[c] * w0.z; acc[3] += xs[c] * w0.w;
      acc[4] += xs[c] * w1.x; acc[5] += xs[c] * w1.y;
      acc[6] += xs[c] * w1.z; acc[7] += xs[c] * w1.w;
    }
  }
#pragma unroll
  for (int off = 32; off >= 1; off >>= 1)
#pragma unroll
    for (int e = 0; e < 8; ++e) acc[e] += __shfl_down(acc[e], off);
  if (l == 0) {
    float v[8];
#pragma unroll
    for (int e = 0; e < 8; ++e) v[e] = acc[e] + bg[e];
    int i0 = 0;
#pragma unroll
    for (int e = 1; e < 8; ++e) if (v[e] > v[i0]) i0 = e;
    int i1 = -1;
#pragma unroll
    for (int e = 0; e < 8; ++e) if (e != i0 && (i1 < 0 || v[e] > v[i1])) i1 = e;
    float e1 = expf(v[i1] - v[i0]);
    float s = 1.f + e1;
    topi[t * 2 + 0] = i0; topi[t * 2 + 1] = i1;
    topw[t * 2 + 0] = 1.f / s; topw[t * 2 + 1] = e1 / s;
    atomicAdd(&cnt[i0], 1);
    atomicAdd(&cnt[i1], 1);
  }
}

// local 256-aligned exclusive scan of cnt (uniform, 8 entries)
__device__ __forceinline__ void local_scan(const int* __restrict__ cnt, int* offs) {
  int o = 0;
#pragma unroll
  for (int e = 0; e < NEXP; ++e) {
    offs[e] = o;
    o += ((cnt[e] + 255) >> 8) << 8;
  }
  offs[NEXP] = o;
}

// ---------------- assign rows ----------------
__global__ __launch_bounds__(256) void assign_kernel(const int* __restrict__ topi,
                                                     const int* __restrict__ cnt,
                                                     int* __restrict__ cursor,
                                                     int* __restrict__ row_of,
                                                     int* __restrict__ token_of) {
  int offs[NEXP + 1];
  local_scan(cnt, offs);
  int id = blockIdx.x * 256 + threadIdx.x;
  if (id >= TOK * 2) return;
  int e = topi[id];
  int slot = atomicAdd(&cursor[e], 1);
  int row = offs[e] + slot;
  row_of[id] = row;
  token_of[row] = id >> 1;
}

// ---- grouped GEMM: 256x256, BK=32, 4 LDS buffers, 3-tile-deep counted-vmcnt ----
// A: bf16 [rows][K] (INDIRECT: tile row -> token_of gather)
// B: bf16 [NEXP][N][K] (k-contiguous)
// out: bf16 [rows][N] = GELU ? gelu(acc+bias) : acc+bias, LDS-staged coalesced.
// LDS: A [4buf][256r][64B] at 0..64K, B same at 64K..128K; read swizzle
// chunk^=(row&3) with inverse-swizzled global source (linear gll dest).
template<bool INDIRECT, bool GELU, int N, int K>
__global__ __launch_bounds__(512)
void moe_gemm(const unsigned short* __restrict__ A,
              const unsigned short* __restrict__ B0,
              const float* __restrict__ bias0,
              unsigned short* __restrict__ out,
              const int* __restrict__ cnt,
              const int* __restrict__ token_of) {
  int offs[NEXP + 1];
  local_scan(cnt, offs);

  // XCD-chunked bijective swizzle (nwg % 8 == 0 for both grids)
  int nwg = gridDim.x * gridDim.y;
  int orig = blockIdx.y * gridDim.x + blockIdx.x;
  int vid = (orig & 7) * (nwg >> 3) + (orig >> 3);
  int bx = vid % gridDim.x, by = vid / gridDim.x;

  int row0 = by * BM;
  if (row0 >= offs[NEXP]) return;
  int e = 0;
  while (row0 >= offs[e + 1]) ++e;
  const unsigned short* Bp = B0 + (size_t)e * N * K;
  const float* bias = bias0 + (size_t)e * N;
  int n0 = bx * BN;

  __shared__ __align__(16) char sm[131072];

  int tid = threadIdx.x;
  int w = tid >> 6, l = tid & 63;
  int lrow = l & 15, kq = l >> 4;
  int wm = w & 1, wn = w >> 1;            // 2M x 4N waves; per-wave C = 128x64
  int csw = ((l & 3) ^ ((l >> 2) & 3)) * 16;   // inverse-swizzled chunk byte

  // staging: per thread 2 gll for A + 2 for B per tile; rows w*32+j*16+(l>>2)
  const char* srcA[2];
  const char* srcB[2];
#pragma unroll
  for (int j = 0; j < 2; ++j) {
    int gr = w * 32 + j * 16 + (l >> 2);
    int ar;
    if (INDIRECT) { int t0 = token_of[row0 + gr]; ar = t0 < 0 ? 0 : t0; }
    else ar = row0 + gr;
    srcA[j] = (const char*)(A + (size_t)ar * K) + csw;
    srcB[j] = (const char*)(Bp + (size_t)(n0 + gr) * K) + csw;
  }

  auto issueA = [&](int t) {
    int dsto = (t & 3) * 16384 + w * 2048;
    int kb = t * 64;
    gll16(srcA[0] + kb, sm + dsto);
    gll16(srcA[1] + kb, sm + dsto + 1024);
  };
  auto issueB = [&](int t) {
    int dsto = 65536 + (t & 3) * 16384 + w * 2048;
    int kb = t * 64;
    gll16(srcB[0] + kb, sm + dsto);
    gll16(srcB[1] + kb, sm + dsto + 1024);
  };
  auto rdA = [&](int bufo, int mi) -> bfrag {
    int row = wm * 128 + mi * 16 + lrow;
    int cc = kq ^ (row & 3);
    return *(const bfrag*)(sm + bufo + row * 64 + cc * 16);
  };
  auto rdB = [&](int bufo, int nj) -> bfrag {
    int row = wn * 64 + nj * 16 + lrow;
    int cc = kq ^ (row & 3);
    return *(const bfrag*)(sm + 65536 + bufo + row * 64 + cc * 16);
  };

  ffrag acc[8][4];
#pragma unroll
  for (int i = 0; i < 8; ++i)
#pragma unroll
    for (int j = 0; j < 4; ++j) acc[i][j] = (ffrag){0.f, 0.f, 0.f, 0.f};

  // prologue: tiles 0,1,2 in flight; drain tile 0 (leave 8)
  issueA(0); issueB(0); issueA(1); issueB(1); issueA(2); issueB(2);
  asm volatile("s_waitcnt vmcnt(8)" ::: "memory");
  __builtin_amdgcn_s_barrier();

  const int NT = K / 32;
  bfrag a[8], b[2];
#pragma unroll 4
  for (int t = 0; t < NT; ++t) {
    const int bufo = (t & 3) * 16384;
    // ---- phase 0: all A frags + B[0..1]; 16 MFMA ----
#pragma unroll
    for (int mi = 0; mi < 8; ++mi) a[mi] = rdA(bufo, mi);
#pragma unroll
    for (int nj = 0; nj < 2; ++nj) b[nj] = rdB(bufo, nj);
    if (t + 3 < NT) issueA(t + 3);
    __builtin_amdgcn_s_setprio(1);
#pragma unroll
    for (int mi = 0; mi < 8; ++mi)
#pragma unroll
      for (int nj = 0; nj < 2; ++nj)
        acc[mi][nj] = __builtin_amdgcn_mfma_f32_16x16x32_bf16(a[mi], b[nj], acc[mi][nj], 0, 0, 0);
    __builtin_amdgcn_s_setprio(0);
    __builtin_amdgcn_s_barrier();
    // ---- phase 1: B[2..3]; 16 MFMA; counted drain of tile t+1 ----
#pragma unroll
    for (int nj = 0; nj < 2; ++nj) b[nj] = rdB(bufo, nj + 2);
    if (t + 3 < NT) issueB(t + 3);
    __builtin_amdgcn_s_setprio(1);
#pragma unroll
    for (int mi = 0; mi < 8; ++mi)
#pragma unroll
      for (int nj = 0; nj < 2; ++nj)
        acc[mi][nj + 2] = __builtin_amdgcn_mfma_f32_16x16x32_bf16(a[mi], b[nj], acc[mi][nj + 2], 0, 0, 0);
    __builtin_amdgcn_s_setprio(0);
    if (t + 3 < NT)      { asm volatile("s_waitcnt vmcnt(8)" ::: "memory"); }
    else if (t + 2 < NT) { asm volatile("s_waitcnt vmcnt(4)" ::: "memory"); }
    else if (t + 1 < NT) { asm volatile("s_waitcnt vmcnt(0)" ::: "memory"); }
    __builtin_amdgcn_s_barrier();
  }

  // epilogue: bias (+gelu), bf16, LDS-staged coalesced store
  __syncthreads();
  unsigned short* ht = (unsigned short*)sm;   // [256][256] bf16 = 128 KB
#pragma unroll
  for (int nj = 0; nj < 4; ++nj) {
    int col = wn * 64 + nj * 16 + lrow;
    float bj = bias[n0 + col];
#pragma unroll
    for (int mi = 0; mi < 8; ++mi) {
      int rl = wm * 128 + mi * 16 + kq * 4;
#pragma unroll
      for (int r = 0; r < 4; ++r) {
        float v = acc[mi][nj][r] + bj;
        if (GELU) {
          float z = 1.5957691216f * (v + 0.044715f * v * v * v);
          v = v / (1.0f + __expf(-z));
        }
        ht[(rl + r) * 256 + col] = f2bf(v);
      }
    }
  }
  __syncthreads();
#pragma unroll
  for (int it = 0; it < 16; ++it) {
    int s = it * 512 + tid;
    int row = s >> 5, c = (s & 31) * 8;
    us8 v = *(const us8*)(ht + row * 256 + c);
    *(us8*)&out[(size_t)(row0 + row) * N + n0 + c] = v;
  }
}

// ---------------- combine (y is bf16) ----------------
__global__ __launch_bounds__(256) void combine_kernel(const unsigned short* __restrict__ y,
                                                      const int* __restrict__ row_of,
                                                      const float* __restrict__ topw,
                                                      float* __restrict__ out) {
  int t = blockIdx.x;
  int r0 = row_of[t * 2 + 0], r1 = row_of[t * 2 + 1];
  float w0 = topw[t * 2 + 0], w1 = topw[t * 2 + 1];
  const ushort4* y0 = (const ushort4*)(y + (size_t)r0 * DDIM);
  const ushort4* y1 = (const ushort4*)(y + (size_t)r1 * DDIM);
  float4* o = (float4*)(out + (size_t)t * DDIM);
  int i = threadIdx.x;
  ushort4 a = y0[i], b = y1[i];
  float4 r = { w0 * bf2f(a.x) + w1 * bf2f(b.x), w0 * bf2f(a.y) + w1 * bf2f(b.y),
               w0 * bf2f(a.z) + w1 * bf2f(b.z), w0 * bf2f(a.w) + w1 * bf2f(b.w) };
  o[i] = r;
}

extern "C" void kernel_launch(void* const* d_in, const int* in_sizes, int n_in,
                              void* d_out, int out_size, void* d_ws, size_t ws_size,
                              hipStream_t stream) {
  const float* x  = (const float*)d_in[0];
  const float* Wg = (const float*)d_in[1];
  const float* bg = (const float*)d_in[2];
  const float* W1 = (const float*)d_in[3];
  const float* b1 = (const float*)d_in[4];
  const float* W2 = (const float*)d_in[5];
  const float* b2 = (const float*)d_in[6];
  float* out = (float*)d_out;

  size_t off = 0;
  char* base = (char*)d_ws;
  auto alloc = [&](size_t bytes) -> void* {
    void* p = base + off;
    off += (bytes + 255) & ~(size_t)255;
    return p;
  };
  unsigned short* xb  = (unsigned short*)alloc((size_t)TOK * DDIM * 2);
  unsigned short* w1t = (unsigned short*)alloc((size_t)NEXP * HDIM * DDIM * 2);
  unsigned short* w2t = (unsigned short*)alloc((size_t)NEXP * DDIM * HDIM * 2);
  unsigned short* h   = (unsigned short*)alloc((size_t)CAP * HDIM * 2);
  unsigned short* y   = (unsigned short*)alloc((size_t)CAP * DDIM * 2);
  int*   topi     = (int*)alloc((size_t)TOK * 2 * 4);
  float* topw     = (float*)alloc((size_t)TOK * 2 * 4);
  int*   row_of   = (int*)alloc((size_t)TOK * 2 * 4);
  int*   token_of = (int*)alloc((size_t)CAP * 4);
  int*   cntcur   = (int*)alloc(64);      // cnt = [0..7], cursor = [8..15]
  if (off > ws_size) return;

  int* cnt = cntcur;
  int* cursor = cntcur + 8;

  hipMemsetAsync(cntcur, 0, 64, stream);
  hipMemsetAsync(token_of, 0xFF, (size_t)CAP * 4, stream);

  transpose_cvt2<<<16384, 256, 0, stream>>>(W1, w1t, W2, w2t);
  gate_kernel<<<TOK, 64, 0, stream>>>(x, Wg, bg, xb, topi, topw, cnt);
  assign_kernel<<<(TOK * 2) / 256, 256, 0, stream>>>(topi, cnt, cursor, row_of, token_of);

  moe_gemm<true, true, HDIM, DDIM><<<dim3(HDIM / BN, NMT), 512, 0, stream>>>(
      xb, w1t, b1, h, cnt, token_of);
  moe_gemm<false, false, DDIM, HDIM><<<dim3(DDIM / BN, NMT), 512, 0, stream>>>(
      h, w2t, b2, y, cnt, token_of);

  combine_kernel<<<TOK, 256, 0, stream>>>(y, row_of, topw, out);
}

// Round 7
// 727.575 us; speedup vs baseline: 1.0649x; 1.0649x over previous
//
#include <hip/hip_runtime.h>
#include <math.h>

#define TOK   8192
#define DDIM  1024
#define HDIM  4096
#define NEXP  8
#define CAP   17408   /* 16384 + 8*128 padding, = 136*128 */
#define NMT   136
#define BM    128
#define BN    128
#define BK    32      /* 64 bytes */

typedef __attribute__((ext_vector_type(8))) short  bfrag;
typedef __attribute__((ext_vector_type(4))) float  ffrag;
typedef __attribute__((ext_vector_type(8))) unsigned short us8;

__device__ __forceinline__ unsigned short f2bf(float f) {
  unsigned int u = __float_as_uint(f);
  u = (u + 0x7FFFu + ((u >> 16) & 1u)) >> 16;   // RNE
  return (unsigned short)u;
}
__device__ __forceinline__ float bf2f(unsigned short u) {
  return __uint_as_float((unsigned int)u << 16);
}

__device__ __forceinline__ void gll16(const void* g, void* l) {
  __builtin_amdgcn_global_load_lds(
      (const __attribute__((address_space(1))) unsigned int*)g,
      (__attribute__((address_space(3))) unsigned int*)l,
      16, 0, 0);
}

// ---- fused transpose+cvt: W1 [8][1024][4096] and W2 [8][4096][1024] -> [C][R] bf16
__global__ __launch_bounds__(256) void transpose_cvt2(const float* __restrict__ W1,
                                                      unsigned short* __restrict__ w1t,
                                                      const float* __restrict__ W2,
                                                      unsigned short* __restrict__ w2t) {
  int bid = blockIdx.x;
  const float* in; unsigned short* out; int R, C, tile;
  if (bid < 8192) { in = W1; out = w1t; R = DDIM; C = HDIM; tile = bid; }
  else            { in = W2; out = w2t; R = HDIM; C = DDIM; tile = bid - 8192; }
  int e = tile >> 10;
  int t = tile & 1023;
  int tpr = C >> 6;
  int ty = t / tpr, tx = t % tpr;
  size_t bo = (size_t)e * R * C;
  in += bo; out += bo;
  int r0 = ty * 64, c0 = tx * 64;

  __shared__ float t4[4096];
  int tid = threadIdx.x;
  int tr = tid >> 4;
  int tc4 = (tid & 15) * 4;
#pragma unroll
  for (int it = 0; it < 4; ++it) {
    int r = tr + it * 16;
    float4 v = *(const float4*)&in[(size_t)(r0 + r) * C + c0 + tc4];
    t4[r * 64 + ((tc4 + 0) ^ r)] = v.x;
    t4[r * 64 + ((tc4 + 1) ^ r)] = v.y;
    t4[r * 64 + ((tc4 + 2) ^ r)] = v.z;
    t4[r * 64 + ((tc4 + 3) ^ r)] = v.w;
  }
  __syncthreads();
  int og0 = (tid & 7) * 8;
  int oc0 = tid >> 3;
#pragma unroll
  for (int it = 0; it < 2; ++it) {
    int oc = oc0 + it * 32;
    us8 v;
#pragma unroll
    for (int j = 0; j < 8; ++j) {
      int r = og0 + j;
      v[j] = (short)f2bf(t4[r * 64 + (oc ^ r)]);
    }
    *(us8*)&out[(size_t)(c0 + oc) * R + r0 + og0] = v;
  }
}

// ------- gate: 4 tokens per 256-thr block; logits, top-2, softmax, x->bf16 ---
__global__ __launch_bounds__(256) void gate_kernel(const float* __restrict__ x,
                                                   const float* __restrict__ Wg,
                                                   const float* __restrict__ bg,
                                                   unsigned short* __restrict__ xb,
                                                   int* __restrict__ topi,
                                                   float* __restrict__ topw,
                                                   int* __restrict__ cnt) {
  int w = threadIdx.x >> 6, l = threadIdx.x & 63;
  int t = blockIdx.x * 4 + w;
  const float4* xr = (const float4*)(x + (size_t)t * DDIM);
  ushort4* xo = (ushort4*)(xb + (size_t)t * DDIM);
  const float4* wg = (const float4*)Wg;
  float acc[8];
#pragma unroll
  for (int e = 0; e < 8; ++e) acc[e] = 0.f;
#pragma unroll
  for (int g = 0; g < 4; ++g) {
    int idx = g * 64 + l;
    float4 xv = xr[idx];
    xo[idx] = (ushort4){ f2bf(xv.x), f2bf(xv.y), f2bf(xv.z), f2bf(xv.w) };
    int dbase = idx * 4;
    float xs[4] = { xv.x, xv.y, xv.z, xv.w };
#pragma unroll
    for (int c = 0; c < 4; ++c) {
      float4 w0 = wg[(dbase + c) * 2 + 0];
      float4 w1 = wg[(dbase + c) * 2 + 1];
      acc[0] += xs[c] * w0.x; acc[1] += xs[c] * w0.y;
      acc[2] += xs[c] * w0.z; acc[3] += xs[c] * w0.w;
      acc[4] += xs[c] * w1.x; acc[5] += xs[c] * w1.y;
      acc[6] += xs[c] * w1.z; acc[7] += xs[c] * w1.w;
    }
  }
#pragma unroll
  for (int off = 32; off >= 1; off >>= 1)
#pragma unroll
    for (int e = 0; e < 8; ++e) acc[e] += __shfl_down(acc[e], off);
  if (l == 0) {
    float v[8];
#pragma unroll
    for (int e = 0; e < 8; ++e) v[e] = acc[e] + bg[e];
    int i0 = 0;
#pragma unroll
    for (int e = 1; e < 8; ++e) if (v[e] > v[i0]) i0 = e;
    int i1 = -1;
#pragma unroll
    for (int e = 0; e < 8; ++e) if (e != i0 && (i1 < 0 || v[e] > v[i1])) i1 = e;
    float e1 = expf(v[i1] - v[i0]);
    float s = 1.f + e1;
    topi[t * 2 + 0] = i0; topi[t * 2 + 1] = i1;
    topw[t * 2 + 0] = 1.f / s; topw[t * 2 + 1] = e1 / s;
    atomicAdd(&cnt[i0], 1);
    atomicAdd(&cnt[i1], 1);
  }
}

// ---------------- offsets: 128-aligned exclusive scan ----------------
__global__ void scan_kernel(const int* __restrict__ cnt, int* __restrict__ offsets) {
  if (threadIdx.x == 0 && blockIdx.x == 0) {
    int o = 0;
#pragma unroll
    for (int e = 0; e < NEXP; ++e) {
      offsets[e] = o;
      o += ((cnt[e] + 127) >> 7) << 7;
    }
    offsets[NEXP] = o;
  }
}

// ---------------- assign rows ----------------
__global__ __launch_bounds__(256) void assign_kernel(const int* __restrict__ topi,
                                                     const int* __restrict__ offsets,
                                                     int* __restrict__ cursor,
                                                     int* __restrict__ row_of,
                                                     int* __restrict__ token_of) {
  int id = blockIdx.x * 256 + threadIdx.x;
  if (id >= TOK * 2) return;
  int e = topi[id];
  int slot = atomicAdd(&cursor[e], 1);
  int row = offsets[e] + slot;
  row_of[id] = row;
  token_of[row] = id >> 1;
}

// ---- grouped GEMM (r2 structure + 3-buffer counted-vmcnt + 2-way swizzle) ----
// A: bf16 [rows][K] (INDIRECT: tile row -> token_of gather)
// B: bf16 [NEXP][N][K] (k-contiguous)
// out: bf16 [rows][N] = GELU ? gelu(acc+bias) : acc+bias, LDS-staged store.
// LDS layout per buf (8 KB per matrix): addr(row,kq) = (row>>1)*128 +
//   ((((row&1)*4+kq) ^ ((row>>1)&7)) * 16)  -- 2-way-free reads; linear gll
//   dest with the inverse permutation folded into the per-lane global source.
template<bool INDIRECT, bool GELU>
__global__ __launch_bounds__(256)
void moe_gemm(const unsigned short* __restrict__ A,
              const unsigned short* __restrict__ B0,
              const float* __restrict__ bias0,
              unsigned short* __restrict__ out,
              int N, int K,
              const int* __restrict__ offsets,
              const int* __restrict__ token_of) {
  // XCD-chunked bijective swizzle (nwg % 8 == 0 for both grids)
  int nwg = gridDim.x * gridDim.y;
  int orig = blockIdx.y * gridDim.x + blockIdx.x;
  int vid = (orig & 7) * (nwg >> 3) + (orig >> 3);
  int bx = vid % gridDim.x, by = vid / gridDim.x;

  int row0 = by * BM;
  if (row0 >= offsets[NEXP]) return;
  int e = 0;
  while (row0 >= offsets[e + 1]) ++e;
  const unsigned short* B = B0 + (size_t)e * N * K;
  const float* bias = bias0 + (size_t)e * N;
  int n0 = bx * BN;

  // A bufs: [0, 24576); B bufs: [24576, 49152); 8192 B per buf per matrix
  __shared__ __align__(16) char sm[49152];

  int tid = threadIdx.x;
  int w = tid >> 6, l = tid & 63;
  int lrow = l & 15, kq = l >> 4;
  int wm = w >> 1, wn = w & 1;

  // ---- staging source (inverse-swizzled): lane l of segment s covers
  // linear chunk n = s*64 + l -> (row, kchunk) via the involution.
  int c2 = (l & 7) ^ (l >> 3);
  int rloc = ((l >> 3) << 1) + (c2 >> 2);   // row within 16-row segment
  int ksw = (c2 & 3) * 16;                  // k-chunk byte offset
  int s0 = 2 * w, s1 = 2 * w + 1;           // wave stages segments s0, s1

  int gr0 = row0 + s0 * 16 + rloc, gr1 = row0 + s1 * 16 + rloc;
  int ar0, ar1;
  if (INDIRECT) {
    int t0 = token_of[gr0]; ar0 = t0 < 0 ? 0 : t0;
    int t1 = token_of[gr1]; ar1 = t1 < 0 ? 0 : t1;
  } else { ar0 = gr0; ar1 = gr1; }
  const char* srcA0 = (const char*)(A + (size_t)ar0 * K) + ksw;
  const char* srcA1 = (const char*)(A + (size_t)ar1 * K) + ksw;
  const char* srcB0 = (const char*)(B + (size_t)(n0 + s0 * 16 + rloc) * K) + ksw;
  const char* srcB1 = (const char*)(B + (size_t)(n0 + s1 * 16 + rloc) * K) + ksw;

  auto stage = [&](int buf, int kb) {
    gll16(srcA0 + kb, sm + buf * 8192 + s0 * 1024);
    gll16(srcA1 + kb, sm + buf * 8192 + s1 * 1024);
    gll16(srcB0 + kb, sm + 24576 + buf * 8192 + s0 * 1024);
    gll16(srcB1 + kb, sm + 24576 + buf * 8192 + s1 * 1024);
  };

  // ---- read-side swizzled offsets (precomputed, static-indexed)
  int offA[4], offB[4];
#pragma unroll
  for (int i = 0; i < 4; ++i) {
    int ra = wm * 64 + i * 16 + lrow;
    offA[i] = (ra >> 1) * 128 + (((((ra & 1) << 2) + kq) ^ ((ra >> 1) & 7)) << 4);
    int rb = wn * 64 + i * 16 + lrow;
    offB[i] = 24576 + (rb >> 1) * 128 + (((((rb & 1) << 2) + kq) ^ ((rb >> 1) & 7)) << 4);
  }

  ffrag acc[4][4];
#pragma unroll
  for (int i = 0; i < 4; ++i)
#pragma unroll
    for (int j = 0; j < 4; ++j) acc[i][j] = (ffrag){0.f, 0.f, 0.f, 0.f};

  auto compute = [&](int buf) {
    int ab = buf * 8192;
    bfrag a[4], b[4];
#pragma unroll
    for (int i = 0; i < 4; ++i) a[i] = *(const bfrag*)(sm + ab + offA[i]);
#pragma unroll
    for (int j = 0; j < 4; ++j) b[j] = *(const bfrag*)(sm + ab + offB[j]);
#pragma unroll
    for (int i = 0; i < 4; ++i)
#pragma unroll
      for (int j = 0; j < 4; ++j)
        acc[i][j] = __builtin_amdgcn_mfma_f32_16x16x32_bf16(a[i], b[j], acc[i][j], 0, 0, 0);
  };

  // prologue: tiles 0,1 in flight; wait tile 0 (own 4 oldest loads)
  stage(0, 0); stage(1, 64);
  asm volatile("s_waitcnt vmcnt(4)" ::: "memory");
  __builtin_amdgcn_s_barrier();

  int nk = K / BK;
  int cur = 0;
  for (int kt = 0; kt < nk; ++kt) {
    int nxt2 = cur + 2; if (nxt2 >= 3) nxt2 -= 3;
    if (kt + 2 < nk) stage(nxt2, (kt + 2) * 64);
    compute(cur);
    if (kt + 1 < nk) {
      if (kt + 2 < nk) { asm volatile("s_waitcnt vmcnt(4)" ::: "memory"); }
      else             { asm volatile("s_waitcnt vmcnt(0)" ::: "memory"); }
    }
    __builtin_amdgcn_s_barrier();
    ++cur; if (cur == 3) cur = 0;
  }

  // epilogue: bias (+gelu) -> bf16 staged in LDS, coalesced 16B stores
  unsigned short* ht = (unsigned short*)sm;   // [128][128] bf16 = 32 KB
#pragma unroll
  for (int j = 0; j < 4; ++j) {
    int col = wn * 64 + j * 16 + lrow;
    float bj = bias[n0 + col];
#pragma unroll
    for (int i = 0; i < 4; ++i) {
      int rl = wm * 64 + i * 16 + kq * 4;
#pragma unroll
      for (int r = 0; r < 4; ++r) {
        float v = acc[i][j][r] + bj;
        if (GELU) {
          float z = 1.5957691216f * (v + 0.044715f * v * v * v);
          v = v / (1.0f + __expf(-z));
        }
        ht[(rl + r) * BN + col] = f2bf(v);
      }
    }
  }
  __syncthreads();
#pragma unroll
  for (int it = 0; it < 8; ++it) {
    int c = it * 256 + tid;
    int row = c >> 4;
    int cc = (c & 15) * 8;
    us8 v = *(const us8*)&ht[row * BN + cc];
    *(us8*)&out[(size_t)(row0 + row) * N + n0 + cc] = v;
  }
}

// ---------------- combine (y is bf16) ----------------
__global__ __launch_bounds__(256) void combine_kernel(const unsigned short* __restrict__ y,
                                                      const int* __restrict__ row_of,
                                                      const float* __restrict__ topw,
                                                      float* __restrict__ out) {
  int t = blockIdx.x;
  int r0 = row_of[t * 2 + 0], r1 = row_of[t * 2 + 1];
  float w0 = topw[t * 2 + 0], w1 = topw[t * 2 + 1];
  const ushort4* y0 = (const ushort4*)(y + (size_t)r0 * DDIM);
  const ushort4* y1 = (const ushort4*)(y + (size_t)r1 * DDIM);
  float4* o = (float4*)(out + (size_t)t * DDIM);
  int i = threadIdx.x;
  ushort4 a = y0[i], b = y1[i];
  float4 r = { w0 * bf2f(a.x) + w1 * bf2f(b.x), w0 * bf2f(a.y) + w1 * bf2f(b.y),
               w0 * bf2f(a.z) + w1 * bf2f(b.z), w0 * bf2f(a.w) + w1 * bf2f(b.w) };
  o[i] = r;
}

extern "C" void kernel_launch(void* const* d_in, const int* in_sizes, int n_in,
                              void* d_out, int out_size, void* d_ws, size_t ws_size,
                              hipStream_t stream) {
  const float* x  = (const float*)d_in[0];
  const float* Wg = (const float*)d_in[1];
  const float* bg = (const float*)d_in[2];
  const float* W1 = (const float*)d_in[3];
  const float* b1 = (const float*)d_in[4];
  const float* W2 = (const float*)d_in[5];
  const float* b2 = (const float*)d_in[6];
  float* out = (float*)d_out;

  size_t off = 0;
  char* base = (char*)d_ws;
  auto alloc = [&](size_t bytes) -> void* {
    void* p = base + off;
    off += (bytes + 255) & ~(size_t)255;
    return p;
  };
  unsigned short* xb  = (unsigned short*)alloc((size_t)TOK * DDIM * 2);
  unsigned short* w1t = (unsigned short*)alloc((size_t)NEXP * HDIM * DDIM * 2);
  unsigned short* w2t = (unsigned short*)alloc((size_t)NEXP * DDIM * HDIM * 2);
  unsigned short* h   = (unsigned short*)alloc((size_t)CAP * HDIM * 2);
  unsigned short* y   = (unsigned short*)alloc((size_t)CAP * DDIM * 2);
  int*   topi     = (int*)alloc((size_t)TOK * 2 * 4);
  float* topw     = (float*)alloc((size_t)TOK * 2 * 4);
  int*   row_of   = (int*)alloc((size_t)TOK * 2 * 4);
  int*   token_of = (int*)alloc((size_t)CAP * 4);
  int*   cntcur   = (int*)alloc(64);      // cnt = [0..7], cursor = [8..15]
  int*   offsets  = (int*)alloc(64);
  if (off > ws_size) return;

  int* cnt = cntcur;
  int* cursor = cntcur + 8;

  hipMemsetAsync(cntcur, 0, 64, stream);
  hipMemsetAsync(token_of, 0xFF, (size_t)CAP * 4, stream);

  transpose_cvt2<<<16384, 256, 0, stream>>>(W1, w1t, W2, w2t);
  gate_kernel<<<TOK / 4, 256, 0, stream>>>(x, Wg, bg, xb, topi, topw, cnt);
  scan_kernel<<<1, 64, 0, stream>>>(cnt, offsets);
  assign_kernel<<<(TOK * 2) / 256, 256, 0, stream>>>(topi, offsets, cursor,
                                                     row_of, token_of);

  moe_gemm<true, true><<<dim3(HDIM / BN, NMT), 256, 0, stream>>>(
      xb, w1t, b1, h, HDIM, DDIM, offsets, token_of);
  moe_gemm<false, false><<<dim3(DDIM / BN, NMT), 256, 0, stream>>>(
      h, w2t, b2, y, DDIM, HDIM, offsets, token_of);

  combine_kernel<<<TOK, 256, 0, stream>>>(y, row_of, topw, out);
}

// Round 8
// 702.014 us; speedup vs baseline: 1.1037x; 1.0364x over previous
//
#include <hip/hip_runtime.h>
#include <math.h>

#define TOK   8192
#define DDIM  1024
#define HDIM  4096
#define NEXP  8
#define CAP   17408   /* 16384 + 8*128 padding, = 136*128 */
#define NMT   136
#define BM    128
#define BN    128
#define BK    32      /* 64 bytes */

typedef __attribute__((ext_vector_type(8))) short  bfrag;
typedef __attribute__((ext_vector_type(4))) float  ffrag;
typedef __attribute__((ext_vector_type(8))) unsigned short us8;

__device__ __forceinline__ unsigned short f2bf(float f) {
  unsigned int u = __float_as_uint(f);
  u = (u + 0x7FFFu + ((u >> 16) & 1u)) >> 16;   // RNE
  return (unsigned short)u;
}
__device__ __forceinline__ float bf2f(unsigned short u) {
  return __uint_as_float((unsigned int)u << 16);
}

__device__ __forceinline__ void gll16(const void* g, void* l) {
  __builtin_amdgcn_global_load_lds(
      (const __attribute__((address_space(1))) unsigned int*)g,
      (__attribute__((address_space(3))) unsigned int*)l,
      16, 0, 0);
}

// ---- union prep kernel ----
// blocks [0, 16384): transpose+cvt W1 [8][1024][4096] / W2 [8][4096][1024] -> [C][R] bf16
// blocks [16384, 18432): gate (4 tokens/block): logits, top-2, softmax, x->bf16,
//                        cnt histogram; also clears token_of.
__global__ __launch_bounds__(256)
void prep_kernel(const float* __restrict__ W1, unsigned short* __restrict__ w1t,
                 const float* __restrict__ W2, unsigned short* __restrict__ w2t,
                 const float* __restrict__ x,  const float* __restrict__ Wg,
                 const float* __restrict__ bg, unsigned short* __restrict__ xb,
                 int* __restrict__ topi, float* __restrict__ topw,
                 int* __restrict__ cnt, int* __restrict__ token_of) {
  int bid = blockIdx.x;
  int tid = threadIdx.x;
  if (bid < 16384) {
    // ---------------- transpose path ----------------
    const float* in; unsigned short* out; int R, C, tile;
    if (bid < 8192) { in = W1; out = w1t; R = DDIM; C = HDIM; tile = bid; }
    else            { in = W2; out = w2t; R = HDIM; C = DDIM; tile = bid - 8192; }
    int e = tile >> 10;
    int t = tile & 1023;
    int tpr = C >> 6;
    int ty = t / tpr, tx = t % tpr;
    size_t bo = (size_t)e * R * C;
    in += bo; out += bo;
    int r0 = ty * 64, c0 = tx * 64;

    __shared__ float t4[4096];
    int tr = tid >> 4;
    int tc4 = (tid & 15) * 4;
#pragma unroll
    for (int it = 0; it < 4; ++it) {
      int r = tr + it * 16;
      float4 v = *(const float4*)&in[(size_t)(r0 + r) * C + c0 + tc4];
      t4[r * 64 + ((tc4 + 0) ^ r)] = v.x;
      t4[r * 64 + ((tc4 + 1) ^ r)] = v.y;
      t4[r * 64 + ((tc4 + 2) ^ r)] = v.z;
      t4[r * 64 + ((tc4 + 3) ^ r)] = v.w;
    }
    __syncthreads();
    int og0 = (tid & 7) * 8;
    int oc0 = tid >> 3;
#pragma unroll
    for (int it = 0; it < 2; ++it) {
      int oc = oc0 + it * 32;
      us8 v;
#pragma unroll
      for (int j = 0; j < 8; ++j) {
        int r = og0 + j;
        v[j] = (short)f2bf(t4[r * 64 + (oc ^ r)]);
      }
      *(us8*)&out[(size_t)(c0 + oc) * R + r0 + og0] = v;
    }
  } else {
    // ---------------- gate path ----------------
    int gbid = bid - 16384;
    int gid = gbid * 256 + tid;
    if (gid < CAP) token_of[gid] = -1;
    int w = tid >> 6, l = tid & 63;
    int t = gbid * 4 + w;
    const float4* xr = (const float4*)(x + (size_t)t * DDIM);
    ushort4* xo = (ushort4*)(xb + (size_t)t * DDIM);
    const float4* wg = (const float4*)Wg;
    float acc[8];
#pragma unroll
    for (int e = 0; e < 8; ++e) acc[e] = 0.f;
#pragma unroll
    for (int g = 0; g < 4; ++g) {
      int idx = g * 64 + l;
      float4 xv = xr[idx];
      xo[idx] = (ushort4){ f2bf(xv.x), f2bf(xv.y), f2bf(xv.z), f2bf(xv.w) };
      int dbase = idx * 4;
      float xs[4] = { xv.x, xv.y, xv.z, xv.w };
#pragma unroll
      for (int c = 0; c < 4; ++c) {
        float4 w0 = wg[(dbase + c) * 2 + 0];
        float4 w1 = wg[(dbase + c) * 2 + 1];
        acc[0] += xs[c] * w0.x; acc[1] += xs[c] * w0.y;
        acc[2] += xs[c] * w0.z; acc[3] += xs[c] * w0.w;
        acc[4] += xs[c] * w1.x; acc[5] += xs[c] * w1.y;
        acc[6] += xs[c] * w1.z; acc[7] += xs[c] * w1.w;
      }
    }
#pragma unroll
    for (int off = 32; off >= 1; off >>= 1)
#pragma unroll
      for (int e = 0; e < 8; ++e) acc[e] += __shfl_down(acc[e], off);
    if (l == 0) {
      float v[8];
#pragma unroll
      for (int e = 0; e < 8; ++e) v[e] = acc[e] + bg[e];
      int i0 = 0;
#pragma unroll
      for (int e = 1; e < 8; ++e) if (v[e] > v[i0]) i0 = e;
      int i1 = -1;
#pragma unroll
      for (int e = 0; e < 8; ++e) if (e != i0 && (i1 < 0 || v[e] > v[i1])) i1 = e;
      float e1 = expf(v[i1] - v[i0]);
      float s = 1.f + e1;
      topi[t * 2 + 0] = i0; topi[t * 2 + 1] = i1;
      topw[t * 2 + 0] = 1.f / s; topw[t * 2 + 1] = e1 / s;
      atomicAdd(&cnt[i0], 1);
      atomicAdd(&cnt[i1], 1);
    }
  }
}

// local 128-aligned exclusive scan of cnt (uniform, 8 entries)
__device__ __forceinline__ void local_scan(const int* __restrict__ cnt, int* offs) {
  int o = 0;
#pragma unroll
  for (int e = 0; e < NEXP; ++e) {
    offs[e] = o;
    o += ((cnt[e] + 127) >> 7) << 7;
  }
  offs[NEXP] = o;
}

// ---------------- assign rows (local scan) ----------------
__global__ __launch_bounds__(256) void assign_kernel(const int* __restrict__ topi,
                                                     const int* __restrict__ cnt,
                                                     int* __restrict__ cursor,
                                                     int* __restrict__ row_of,
                                                     int* __restrict__ token_of) {
  int offs[NEXP + 1];
  local_scan(cnt, offs);
  int id = blockIdx.x * 256 + threadIdx.x;
  if (id >= TOK * 2) return;
  int e = topi[id];
  int slot = atomicAdd(&cursor[e], 1);
  int row = offs[e] + slot;
  row_of[id] = row;
  token_of[row] = id >> 1;
}

// ---- grouped GEMM (r7 structure: 3-buffer counted-vmcnt + 2-way swizzle,
//      + L2-chunked XCD-aware block ordering) ----
template<bool INDIRECT, bool GELU>
__global__ __launch_bounds__(256)
void moe_gemm(const unsigned short* __restrict__ A,
              const unsigned short* __restrict__ B0,
              const float* __restrict__ bias0,
              unsigned short* __restrict__ out,
              int N, int K,
              const int* __restrict__ cnt,
              const int* __restrict__ token_of) {
  int offsets[NEXP + 1];
  local_scan(cnt, offsets);

  // XCD-chunked bijective swizzle with 8-wide N-tile grouping:
  // per XCD: for n-group g: for m-panel m: for bx in group -> B-tiles (<=2MB)
  // stay L2-resident across the XCD's 17 panels.
  int nwg = gridDim.x * gridDim.y;           // 4352 or 1088; % 8 == 0
  int orig = blockIdx.y * gridDim.x + blockIdx.x;
  int V = nwg >> 3;                           // vids per XCD
  int vid = (orig & 7) * V + (orig >> 3);
  int xcd = vid / V;
  int vloc = vid - xcd * V;
  int P = V / gridDim.x;                      // M-panels per XCD (17)
  int CW = gridDim.x >= 8 ? 8 : gridDim.x;
  int per = P * CW;
  int g = vloc / per;
  int rem = vloc - g * per;
  int m = rem / CW;
  int bx = g * CW + (rem - m * CW);
  int by = xcd * P + m;

  int row0 = by * BM;
  if (row0 >= offsets[NEXP]) return;
  int e = 0;
  while (row0 >= offsets[e + 1]) ++e;
  const unsigned short* B = B0 + (size_t)e * N * K;
  const float* bias = bias0 + (size_t)e * N;
  int n0 = bx * BN;

  // A bufs: [0, 24576); B bufs: [24576, 49152); 8192 B per buf per matrix
  __shared__ __align__(16) char sm[49152];

  int tid = threadIdx.x;
  int w = tid >> 6, l = tid & 63;
  int lrow = l & 15, kq = l >> 4;
  int wm = w >> 1, wn = w & 1;

  // staging source (inverse-swizzled involution; see r7)
  int c2 = (l & 7) ^ (l >> 3);
  int rloc = ((l >> 3) << 1) + (c2 >> 2);
  int ksw = (c2 & 3) * 16;
  int s0 = 2 * w, s1 = 2 * w + 1;

  int gr0 = row0 + s0 * 16 + rloc, gr1 = row0 + s1 * 16 + rloc;
  int ar0, ar1;
  if (INDIRECT) {
    int t0 = token_of[gr0]; ar0 = t0 < 0 ? 0 : t0;
    int t1 = token_of[gr1]; ar1 = t1 < 0 ? 0 : t1;
  } else { ar0 = gr0; ar1 = gr1; }
  const char* srcA0 = (const char*)(A + (size_t)ar0 * K) + ksw;
  const char* srcA1 = (const char*)(A + (size_t)ar1 * K) + ksw;
  const char* srcB0 = (const char*)(B + (size_t)(n0 + s0 * 16 + rloc) * K) + ksw;
  const char* srcB1 = (const char*)(B + (size_t)(n0 + s1 * 16 + rloc) * K) + ksw;

  auto stage = [&](int buf, int kb) {
    gll16(srcA0 + kb, sm + buf * 8192 + s0 * 1024);
    gll16(srcA1 + kb, sm + buf * 8192 + s1 * 1024);
    gll16(srcB0 + kb, sm + 24576 + buf * 8192 + s0 * 1024);
    gll16(srcB1 + kb, sm + 24576 + buf * 8192 + s1 * 1024);
  };

  // read-side swizzled offsets (precomputed, static-indexed)
  int offA[4], offB[4];
#pragma unroll
  for (int i = 0; i < 4; ++i) {
    int ra = wm * 64 + i * 16 + lrow;
    offA[i] = (ra >> 1) * 128 + (((((ra & 1) << 2) + kq) ^ ((ra >> 1) & 7)) << 4);
    int rb = wn * 64 + i * 16 + lrow;
    offB[i] = 24576 + (rb >> 1) * 128 + (((((rb & 1) << 2) + kq) ^ ((rb >> 1) & 7)) << 4);
  }

  ffrag acc[4][4];
#pragma unroll
  for (int i = 0; i < 4; ++i)
#pragma unroll
    for (int j = 0; j < 4; ++j) acc[i][j] = (ffrag){0.f, 0.f, 0.f, 0.f};

  auto compute = [&](int buf) {
    int ab = buf * 8192;
    bfrag a[4], b[4];
#pragma unroll
    for (int i = 0; i < 4; ++i) a[i] = *(const bfrag*)(sm + ab + offA[i]);
#pragma unroll
    for (int j = 0; j < 4; ++j) b[j] = *(const bfrag*)(sm + ab + offB[j]);
#pragma unroll
    for (int i = 0; i < 4; ++i)
#pragma unroll
      for (int j = 0; j < 4; ++j)
        acc[i][j] = __builtin_amdgcn_mfma_f32_16x16x32_bf16(a[i], b[j], acc[i][j], 0, 0, 0);
  };

  // prologue: tiles 0,1 in flight; wait tile 0 (own 4 oldest loads)
  stage(0, 0); stage(1, 64);
  asm volatile("s_waitcnt vmcnt(4)" ::: "memory");
  __builtin_amdgcn_s_barrier();

  int nk = K / BK;
  int cur = 0;
  for (int kt = 0; kt < nk; ++kt) {
    int nxt2 = cur + 2; if (nxt2 >= 3) nxt2 -= 3;
    if (kt + 2 < nk) stage(nxt2, (kt + 2) * 64);
    compute(cur);
    if (kt + 1 < nk) {
      if (kt + 2 < nk) { asm volatile("s_waitcnt vmcnt(4)" ::: "memory"); }
      else             { asm volatile("s_waitcnt vmcnt(0)" ::: "memory"); }
    }
    __builtin_amdgcn_s_barrier();
    ++cur; if (cur == 3) cur = 0;
  }

  // epilogue: bias (+gelu) -> bf16 staged in LDS, coalesced 16B stores
  unsigned short* ht = (unsigned short*)sm;   // [128][128] bf16 = 32 KB
#pragma unroll
  for (int j = 0; j < 4; ++j) {
    int col = wn * 64 + j * 16 + lrow;
    float bj = bias[n0 + col];
#pragma unroll
    for (int i = 0; i < 4; ++i) {
      int rl = wm * 64 + i * 16 + kq * 4;
#pragma unroll
      for (int r = 0; r < 4; ++r) {
        float v = acc[i][j][r] + bj;
        if (GELU) {
          float z = 1.5957691216f * (v + 0.044715f * v * v * v);
          v = v / (1.0f + __expf(-z));
        }
        ht[(rl + r) * BN + col] = f2bf(v);
      }
    }
  }
  __syncthreads();
#pragma unroll
  for (int it = 0; it < 8; ++it) {
    int c = it * 256 + tid;
    int row = c >> 4;
    int cc = (c & 15) * 8;
    us8 v = *(const us8*)&ht[row * BN + cc];
    *(us8*)&out[(size_t)(row0 + row) * N + n0 + cc] = v;
  }
}

// ---------------- combine (y is bf16) ----------------
__global__ __launch_bounds__(256) void combine_kernel(const unsigned short* __restrict__ y,
                                                      const int* __restrict__ row_of,
                                                      const float* __restrict__ topw,
                                                      float* __restrict__ out) {
  int t = blockIdx.x;
  int r0 = row_of[t * 2 + 0], r1 = row_of[t * 2 + 1];
  float w0 = topw[t * 2 + 0], w1 = topw[t * 2 + 1];
  const ushort4* y0 = (const ushort4*)(y + (size_t)r0 * DDIM);
  const ushort4* y1 = (const ushort4*)(y + (size_t)r1 * DDIM);
  float4* o = (float4*)(out + (size_t)t * DDIM);
  int i = threadIdx.x;
  ushort4 a = y0[i], b = y1[i];
  float4 r = { w0 * bf2f(a.x) + w1 * bf2f(b.x), w0 * bf2f(a.y) + w1 * bf2f(b.y),
               w0 * bf2f(a.z) + w1 * bf2f(b.z), w0 * bf2f(a.w) + w1 * bf2f(b.w) };
  o[i] = r;
}

extern "C" void kernel_launch(void* const* d_in, const int* in_sizes, int n_in,
                              void* d_out, int out_size, void* d_ws, size_t ws_size,
                              hipStream_t stream) {
  const float* x  = (const float*)d_in[0];
  const float* Wg = (const float*)d_in[1];
  const float* bg = (const float*)d_in[2];
  const float* W1 = (const float*)d_in[3];
  const float* b1 = (const float*)d_in[4];
  const float* W2 = (const float*)d_in[5];
  const float* b2 = (const float*)d_in[6];
  float* out = (float*)d_out;

  size_t off = 0;
  char* base = (char*)d_ws;
  auto alloc = [&](size_t bytes) -> void* {
    void* p = base + off;
    off += (bytes + 255) & ~(size_t)255;
    return p;
  };
  unsigned short* xb  = (unsigned short*)alloc((size_t)TOK * DDIM * 2);
  unsigned short* w1t = (unsigned short*)alloc((size_t)NEXP * HDIM * DDIM * 2);
  unsigned short* w2t = (unsigned short*)alloc((size_t)NEXP * DDIM * HDIM * 2);
  unsigned short* h   = (unsigned short*)alloc((size_t)CAP * HDIM * 2);
  unsigned short* y   = (unsigned short*)alloc((size_t)CAP * DDIM * 2);
  int*   topi     = (int*)alloc((size_t)TOK * 2 * 4);
  float* topw     = (float*)alloc((size_t)TOK * 2 * 4);
  int*   row_of   = (int*)alloc((size_t)TOK * 2 * 4);
  int*   token_of = (int*)alloc((size_t)CAP * 4);
  int*   cntcur   = (int*)alloc(64);      // cnt = [0..7], cursor = [8..15]
  if (off > ws_size) return;

  int* cnt = cntcur;
  int* cursor = cntcur + 8;

  hipMemsetAsync(cntcur, 0, 64, stream);

  prep_kernel<<<18432, 256, 0, stream>>>(W1, w1t, W2, w2t, x, Wg, bg, xb,
                                         topi, topw, cnt, token_of);
  assign_kernel<<<(TOK * 2) / 256, 256, 0, stream>>>(topi, cnt, cursor,
                                                     row_of, token_of);

  moe_gemm<true, true><<<dim3(HDIM / BN, NMT), 256, 0, stream>>>(
      xb, w1t, b1, h, HDIM, DDIM, cnt, token_of);
  moe_gemm<false, false><<<dim3(DDIM / BN, NMT), 256, 0, stream>>>(
      h, w2t, b2, y, DDIM, HDIM, cnt, token_of);

  combine_kernel<<<TOK, 256, 0, stream>>>(y, row_of, topw, out);
}